// Round 7
// baseline (361.629 us; speedup 1.0000x reference)
//
#include <hip/hip_runtime.h>

#define NNODES 50000
#define NEDGES 800000
#define F_IN   128
#define HID    256
#define NOUT   40
#define NBLK_SCAN ((NNODES + 255) / 256)  // 196
#define NBLK_CAST 6250                     // 50000*128/4/256
#define NBLK_DEG  3125                     // 800000/256
#define NBLK_PREP 432                      // 128 (W1) + 256 (W2) + 48 (Wc)

typedef __attribute__((ext_vector_type(8))) _Float16 f16x8;
typedef __attribute__((ext_vector_type(4))) float f32x4;
typedef __attribute__((ext_vector_type(4))) unsigned short u16x4;

__device__ __forceinline__ unsigned short f2h(float f) {
  return __builtin_bit_cast(unsigned short, (_Float16)f);
}
__device__ __forceinline__ float h2f(unsigned short u) {
  return (float)__builtin_bit_cast(_Float16, u);
}

// ------- fused: x->fp16 cast | degree histogram | weight transpose ---------

__global__ __launch_bounds__(256) void k_pre(const float* __restrict__ X,
                                             unsigned short* __restrict__ Xh,
                                             const int* __restrict__ dst,
                                             int* __restrict__ count,
                                             const float* __restrict__ W1,
                                             const float* __restrict__ W2,
                                             const float* __restrict__ Wc,
                                             unsigned short* __restrict__ T1,
                                             unsigned short* __restrict__ T2,
                                             unsigned short* __restrict__ Tc) {
  int b = blockIdx.x, t = threadIdx.x;
  if (b < NBLK_CAST) {
    int i = b * 256 + t;
    float4 v = *reinterpret_cast<const float4*>(X + (size_t)i * 4);
    ushort4 o;
    o.x = f2h(v.x); o.y = f2h(v.y); o.z = f2h(v.z); o.w = f2h(v.w);
    *reinterpret_cast<ushort4*>(Xh + (size_t)i * 4) = o;
  } else if (b < NBLK_CAST + NBLK_DEG) {
    int e = (b - NBLK_CAST) * 256 + t;
    if (e < NEDGES) atomicAdd(&count[dst[e]], 1);
  } else {
    int pb = b - NBLK_CAST - NBLK_DEG;  // 0..431
    if (pb < 128) {                     // W1 [128][256] -> T1 [256][128]
      int idx = pb * 256 + t;
      int n = idx >> 7, k = idx & 127;
      T1[idx] = f2h(W1[(size_t)k * HID + n]);
    } else if (pb < 384) {              // W2 [256][256] -> T2 [256][256]
      int idx = (pb - 128) * 256 + t;
      int n = idx >> 8, k = idx & 255;
      T2[idx] = f2h(W2[(size_t)k * HID + n]);
    } else {                            // Wc [256][40] -> Tc [48][256] zero-pad
      int idx = (pb - 384) * 256 + t;
      int n = idx >> 8, k = idx & 255;
      float v = (n < NOUT) ? Wc[(size_t)k * NOUT + n] : 0.f;
      Tc[idx] = f2h(v);
    }
  }
}

// ---------------- CSR build ----------------

__global__ __launch_bounds__(256) void k_scan1(const int* __restrict__ count,
                                               int* __restrict__ rowstart,
                                               int* __restrict__ bsum,
                                               float* __restrict__ dinv) {
  __shared__ int tmp[256];
  int t = threadIdx.x;
  int i = blockIdx.x * 256 + t;
  int v = (i < NNODES) ? count[i] : 0;
  if (i < NNODES) dinv[i] = rsqrtf((float)(v + 1));  // +1 self-loop
  tmp[t] = v;
  __syncthreads();
  for (int off = 1; off < 256; off <<= 1) {
    int x = (t >= off) ? tmp[t - off] : 0;
    __syncthreads();
    tmp[t] += x;
    __syncthreads();
  }
  if (i < NNODES) rowstart[i] = tmp[t] - v;  // exclusive
  if (t == 255) bsum[blockIdx.x] = tmp[255];
}

__global__ __launch_bounds__(256) void k_scan2(const int* __restrict__ bsum,
                                               int* __restrict__ boff) {
  __shared__ int tmp[256];
  int t = threadIdx.x;
  int v = (t < NBLK_SCAN) ? bsum[t] : 0;
  tmp[t] = v;
  __syncthreads();
  for (int off = 1; off < 256; off <<= 1) {
    int x = (t >= off) ? tmp[t - off] : 0;
    __syncthreads();
    tmp[t] += x;
    __syncthreads();
  }
  if (t < NBLK_SCAN) boff[t] = tmp[t] - v;  // exclusive
}

__global__ __launch_bounds__(256) void k_scan3(int* __restrict__ rowstart,
                                               const int* __restrict__ boff) {
  int i = blockIdx.x * 256 + threadIdx.x;
  if (i < NNODES) rowstart[i] += boff[blockIdx.x];
  if (i == 0) rowstart[NNODES] = NEDGES;
}

__global__ __launch_bounds__(256) void k_scatter(const int* __restrict__ src,
                                                 const int* __restrict__ dst,
                                                 const int* __restrict__ rowstart,
                                                 int* __restrict__ cursor,
                                                 int* __restrict__ csr) {
  int e = blockIdx.x * 256 + threadIdx.x;
  if (e >= NEDGES) return;
  int d = dst[e];
  int p = rowstart[d] + atomicAdd(&cursor[d], 1);
  csr[p] = src[e];
}

// ---------------- agg layer 1: half-wave fp16 gather (F=128) ----------------
// lanes 0-31 gather edge e, lanes 32-63 edge e+1; 8B/lane; shfl reduce.

__global__ __launch_bounds__(256) void k_agg1(const unsigned short* __restrict__ X,
                                              const int* __restrict__ rowstart,
                                              const int* __restrict__ csr,
                                              const float* __restrict__ dinv,
                                              uint2* __restrict__ Y) {
  int wave = threadIdx.x >> 6, lane = threadIdx.x & 63;
  int node = blockIdx.x * 4 + wave;
  if (node >= NNODES) return;
  int half = lane >> 5, l32 = lane & 31;
  float di = dinv[node];
  float a[4] = {0.f, 0.f, 0.f, 0.f};
  int e = rowstart[node], end = rowstart[node + 1];
  for (; e + 8 <= end; e += 8) {
    int s0 = csr[e + 0 + half], s1 = csr[e + 2 + half];
    int s2 = csr[e + 4 + half], s3 = csr[e + 6 + half];
    float w0 = dinv[s0] * di, w1 = dinv[s1] * di;
    float w2 = dinv[s2] * di, w3 = dinv[s3] * di;
    u16x4 r0 = *reinterpret_cast<const u16x4*>(X + (size_t)s0 * F_IN + l32 * 4);
    u16x4 r1 = *reinterpret_cast<const u16x4*>(X + (size_t)s1 * F_IN + l32 * 4);
    u16x4 r2 = *reinterpret_cast<const u16x4*>(X + (size_t)s2 * F_IN + l32 * 4);
    u16x4 r3 = *reinterpret_cast<const u16x4*>(X + (size_t)s3 * F_IN + l32 * 4);
#pragma unroll
    for (int k = 0; k < 4; k++) {
      a[k] = fmaf(h2f(r0[k]), w0, a[k]);
      a[k] = fmaf(h2f(r1[k]), w1, a[k]);
      a[k] = fmaf(h2f(r2[k]), w2, a[k]);
      a[k] = fmaf(h2f(r3[k]), w3, a[k]);
    }
  }
  for (; e + 2 <= end; e += 2) {
    int s = csr[e + half];
    float w = dinv[s] * di;
    u16x4 r = *reinterpret_cast<const u16x4*>(X + (size_t)s * F_IN + l32 * 4);
#pragma unroll
    for (int k = 0; k < 4; k++) a[k] = fmaf(h2f(r[k]), w, a[k]);
  }
  if (e < end) {  // odd remainder: both halves read it, half 1 weight 0
    int s = csr[e];
    float w = half ? 0.f : dinv[s] * di;
    u16x4 r = *reinterpret_cast<const u16x4*>(X + (size_t)s * F_IN + l32 * 4);
#pragma unroll
    for (int k = 0; k < 4; k++) a[k] = fmaf(h2f(r[k]), w, a[k]);
  }
#pragma unroll
  for (int k = 0; k < 4; k++) a[k] += __shfl_xor(a[k], 32);
  if (half == 0) {
    u16x4 self = *reinterpret_cast<const u16x4*>(X + (size_t)node * F_IN + l32 * 4);
    float dd = di * di;
#pragma unroll
    for (int k = 0; k < 4; k++) a[k] = fmaf(h2f(self[k]), dd, a[k]);
    uint2 o;
    o.x = (unsigned)f2h(a[0]) | ((unsigned)f2h(a[1]) << 16);
    o.y = (unsigned)f2h(a[2]) | ((unsigned)f2h(a[3]) << 16);
    Y[(size_t)node * 32 + l32] = o;
  }
}

// ------- agg layer 2 HALF: gathers dims [off, off+128) of h1 (F=256) -------
// Same half-wave structure as k_agg1; two launches cover the feature dim.

__global__ __launch_bounds__(256) void k_agg2h(const unsigned short* __restrict__ H,
                                               const int* __restrict__ rowstart,
                                               const int* __restrict__ csr,
                                               const float* __restrict__ dinv,
                                               unsigned short* __restrict__ Y,
                                               int off) {
  int wave = threadIdx.x >> 6, lane = threadIdx.x & 63;
  int node = blockIdx.x * 4 + wave;
  if (node >= NNODES) return;
  int half = lane >> 5, l32 = lane & 31;
  float di = dinv[node];
  float a[4] = {0.f, 0.f, 0.f, 0.f};
  const unsigned short* Ho = H + off + l32 * 4;
  int e = rowstart[node], end = rowstart[node + 1];
  for (; e + 8 <= end; e += 8) {
    int s0 = csr[e + 0 + half], s1 = csr[e + 2 + half];
    int s2 = csr[e + 4 + half], s3 = csr[e + 6 + half];
    float w0 = dinv[s0] * di, w1 = dinv[s1] * di;
    float w2 = dinv[s2] * di, w3 = dinv[s3] * di;
    u16x4 r0 = *reinterpret_cast<const u16x4*>(Ho + (size_t)s0 * HID);
    u16x4 r1 = *reinterpret_cast<const u16x4*>(Ho + (size_t)s1 * HID);
    u16x4 r2 = *reinterpret_cast<const u16x4*>(Ho + (size_t)s2 * HID);
    u16x4 r3 = *reinterpret_cast<const u16x4*>(Ho + (size_t)s3 * HID);
#pragma unroll
    for (int k = 0; k < 4; k++) {
      a[k] = fmaf(h2f(r0[k]), w0, a[k]);
      a[k] = fmaf(h2f(r1[k]), w1, a[k]);
      a[k] = fmaf(h2f(r2[k]), w2, a[k]);
      a[k] = fmaf(h2f(r3[k]), w3, a[k]);
    }
  }
  for (; e + 2 <= end; e += 2) {
    int s = csr[e + half];
    float w = dinv[s] * di;
    u16x4 r = *reinterpret_cast<const u16x4*>(Ho + (size_t)s * HID);
#pragma unroll
    for (int k = 0; k < 4; k++) a[k] = fmaf(h2f(r[k]), w, a[k]);
  }
  if (e < end) {
    int s = csr[e];
    float w = half ? 0.f : dinv[s] * di;
    u16x4 r = *reinterpret_cast<const u16x4*>(Ho + (size_t)s * HID);
#pragma unroll
    for (int k = 0; k < 4; k++) a[k] = fmaf(h2f(r[k]), w, a[k]);
  }
#pragma unroll
  for (int k = 0; k < 4; k++) a[k] += __shfl_xor(a[k], 32);
  if (half == 0) {
    u16x4 self = *reinterpret_cast<const u16x4*>(Ho + (size_t)node * HID);
    float dd = di * di;
#pragma unroll
    for (int k = 0; k < 4; k++) a[k] = fmaf(h2f(self[k]), dd, a[k]);
    uint2 o;
    o.x = (unsigned)f2h(a[0]) | ((unsigned)f2h(a[1]) << 16);
    o.y = (unsigned)f2h(a[2]) | ((unsigned)f2h(a[3]) << 16);
    *reinterpret_cast<uint2*>(Y + (size_t)node * HID + off + l32 * 4) = o;
  }
}

// ---------------- fp16 MFMA GEMM, double-buffered, 1 barrier/K-step --------
// C = A[MxK] @ B[KxN] + bias. A fp16 [M][K]; B fp16 transposed [Npad][K].
// BM=BN=128, BK=32, 4 waves (2x2). OMODE: 0 = f32 out, 1 = fp16 out.

template <int RELU, int OMODE>
__global__ __launch_bounds__(256) void k_mgemm(const unsigned short* __restrict__ Ag,
                                               const unsigned short* __restrict__ Btg,
                                               const float* __restrict__ bias,
                                               void* __restrict__ Cout,
                                               int M, int Nc, int K) {
  __shared__ unsigned short Ah[2][128 * 40];
  __shared__ unsigned short Bh[2][128 * 40];
  int tid = threadIdx.x;
  int lane = tid & 63, w = tid >> 6;
  int wr = w >> 1, wc = w & 1;
  int bm = blockIdx.x * 128, bn = blockIdx.y * 128;
  int l15 = lane & 15, kg = lane >> 4;
  int row0 = tid >> 2, kq0 = (tid & 3) * 8;
  int gm0 = bm + row0, gm1 = bm + row0 + 64;

  f32x4 zero = {0.f, 0.f, 0.f, 0.f};
  f32x4 acc[4][4];
#pragma unroll
  for (int i = 0; i < 4; i++)
#pragma unroll
    for (int j = 0; j < 4; j++) acc[i][j] = zero;

  uint4 ra0, ra1, rb0, rb1;
  const uint4 z4 = {0, 0, 0, 0};
#define LOADT(KT)                                                                    \
  {                                                                                  \
    ra0 = z4; ra1 = z4;                                                              \
    if (gm0 < M) ra0 = *reinterpret_cast<const uint4*>(Ag + (size_t)gm0 * K + (KT) + kq0); \
    if (gm1 < M) ra1 = *reinterpret_cast<const uint4*>(Ag + (size_t)gm1 * K + (KT) + kq0); \
    rb0 = *reinterpret_cast<const uint4*>(Btg + (size_t)(bn + row0) * K + (KT) + kq0);     \
    rb1 = *reinterpret_cast<const uint4*>(Btg + (size_t)(bn + row0 + 64) * K + (KT) + kq0);\
  }
#define STORET(B)                                                       \
  {                                                                     \
    *reinterpret_cast<uint4*>(&Ah[B][row0 * 40 + kq0]) = ra0;           \
    *reinterpret_cast<uint4*>(&Ah[B][(row0 + 64) * 40 + kq0]) = ra1;    \
    *reinterpret_cast<uint4*>(&Bh[B][row0 * 40 + kq0]) = rb0;           \
    *reinterpret_cast<uint4*>(&Bh[B][(row0 + 64) * 40 + kq0]) = rb1;    \
  }

  LOADT(0);
  STORET(0);
  __syncthreads();
  int nt = K >> 5, cur = 0;
  for (int t = 0; t < nt; t++) {
    bool pf = (t + 1 < nt);
    if (pf) LOADT((t + 1) << 5);
    f16x8 fa[4], fb[4];
#pragma unroll
    for (int f = 0; f < 4; f++) {
      fa[f] = *reinterpret_cast<const f16x8*>(&Ah[cur][(wr * 64 + f * 16 + l15) * 40 + kg * 8]);
      fb[f] = *reinterpret_cast<const f16x8*>(&Bh[cur][(wc * 64 + f * 16 + l15) * 40 + kg * 8]);
    }
#pragma unroll
    for (int i = 0; i < 4; i++)
#pragma unroll
      for (int j = 0; j < 4; j++)
        acc[i][j] = __builtin_amdgcn_mfma_f32_16x16x32_f16(fa[i], fb[j], acc[i][j], 0, 0, 0);
    if (pf) STORET(cur ^ 1);
    __syncthreads();
    cur ^= 1;
  }
#undef LOADT
#undef STORET

  int r0 = kg * 4;
#pragma unroll
  for (int i = 0; i < 4; i++) {
    int gmBase = bm + wr * 64 + i * 16 + r0;
#pragma unroll
    for (int r = 0; r < 4; r++) {
      int gm = gmBase + r;
      if (gm >= M) continue;
#pragma unroll
      for (int j = 0; j < 4; j++) {
        int gn = bn + wc * 64 + j * 16 + l15;
        if (gn >= Nc) continue;
        float v = acc[i][j][r] + bias[gn];
        if (RELU) v = fmaxf(v, 0.f);
        size_t o = (size_t)gm * Nc + gn;
        if (OMODE == 0) ((float*)Cout)[o] = v;
        else            ((unsigned short*)Cout)[o] = f2h(v);
      }
    }
  }
}

// ---------------- classifier: BM=256, BN=48 (NOUT=40), fp32 out -------------

__global__ __launch_bounds__(256) void k_cls(const unsigned short* __restrict__ Ag,
                                             const unsigned short* __restrict__ Btg,
                                             const float* __restrict__ bias,
                                             float* __restrict__ C, int M) {
  __shared__ unsigned short As[256 * 40];
  __shared__ unsigned short Bs[48 * 40];
  int tid = threadIdx.x;
  int lane = tid & 63, w = tid >> 6;
  int l15 = lane & 15, kg = lane >> 4;
  int bm = blockIdx.x * 256;

  f32x4 zero = {0.f, 0.f, 0.f, 0.f};
  f32x4 acc[4][3];
#pragma unroll
  for (int i = 0; i < 4; i++)
#pragma unroll
    for (int j = 0; j < 3; j++) acc[i][j] = zero;

  for (int kt = 0; kt < HID; kt += 32) {
#pragma unroll
    for (int it = 0; it < 4; it++) {
      int c = tid + it * 256;
      int row = c >> 2, kq = (c & 3) * 8;
      int gm = bm + row;
      uint4 v = {0, 0, 0, 0};
      if (gm < M) v = *reinterpret_cast<const uint4*>(Ag + (size_t)gm * HID + kt + kq);
      *reinterpret_cast<uint4*>(&As[row * 40 + kq]) = v;
    }
    if (tid < 192) {
      int row = tid >> 2, kq = (tid & 3) * 8;
      *reinterpret_cast<uint4*>(&Bs[row * 40 + kq]) =
          *reinterpret_cast<const uint4*>(Btg + (size_t)row * HID + kt + kq);
    }
    __syncthreads();
    f16x8 fa[4], fb[3];
#pragma unroll
    for (int f = 0; f < 4; f++)
      fa[f] = *reinterpret_cast<const f16x8*>(&As[(w * 64 + f * 16 + l15) * 40 + kg * 8]);
#pragma unroll
    for (int j = 0; j < 3; j++)
      fb[j] = *reinterpret_cast<const f16x8*>(&Bs[(j * 16 + l15) * 40 + kg * 8]);
#pragma unroll
    for (int i = 0; i < 4; i++)
#pragma unroll
      for (int j = 0; j < 3; j++)
        acc[i][j] = __builtin_amdgcn_mfma_f32_16x16x32_f16(fa[i], fb[j], acc[i][j], 0, 0, 0);
    __syncthreads();
  }

  int r0 = kg * 4;
#pragma unroll
  for (int i = 0; i < 4; i++) {
    int gmBase = bm + w * 64 + i * 16 + r0;
#pragma unroll
    for (int r = 0; r < 4; r++) {
      int gm = gmBase + r;
      if (gm >= M) continue;
#pragma unroll
      for (int j = 0; j < 3; j++) {
        int gn = j * 16 + l15;
        if (gn >= NOUT) continue;
        C[(size_t)gm * NOUT + gn] = acc[i][j][r] + bias[gn];
      }
    }
  }
}

// ---------------- launch ----------------

extern "C" void kernel_launch(void* const* d_in, const int* in_sizes, int n_in,
                              void* d_out, int out_size, void* d_ws, size_t ws_size,
                              hipStream_t stream) {
  (void)in_sizes; (void)n_in; (void)out_size; (void)ws_size;
  const float* x  = (const float*)d_in[0];
  const float* W1 = (const float*)d_in[1];
  const float* b1 = (const float*)d_in[2];
  const float* W2 = (const float*)d_in[3];
  const float* b2 = (const float*)d_in[4];
  const float* Wc = (const float*)d_in[5];
  const float* bc = (const float*)d_in[6];
  const int* edge = (const int*)d_in[7];
  const int* srcE = edge;
  const int* dstE = edge + NEDGES;
  float* out = (float*)d_out;

  char* ws = (char*)d_ws;
  int*   count    = (int*)(ws + 0);          // 200000 B
  int*   cursor   = (int*)(ws + 200064);
  int*   rowstart = (int*)(ws + 400128);     // 200004 B
  float* dinv     = (float*)(ws + 600320);
  int*   csr      = (int*)(ws + 800384);     // 3.2 MB
  int*   bsum     = (int*)(ws + 4000512);
  int*   boff     = (int*)(ws + 4001536);
  unsigned short* W1t = (unsigned short*)(ws + 4002560);   // 256x128 fp16
  unsigned short* W2t = (unsigned short*)(ws + 4068096);   // 256x256 fp16
  unsigned short* Wct = (unsigned short*)(ws + 4199168);   // 48x256 fp16
  unsigned short* xh  = (unsigned short*)(ws + 4264704);   // 50000x128 fp16
  unsigned short* aggx = (unsigned short*)(ws + 17064704); // 50000x128 fp16
  unsigned short* h1   = (unsigned short*)(ws + 29864704); // 50000x256 fp16
  unsigned short* aggh = (unsigned short*)(ws + 55464704); // 50000x256 fp16
  unsigned short* h2   = (unsigned short*)(ws + 81064704); // 50000x256 fp16

  hipMemsetAsync(ws, 0, 400128, stream);  // count + cursor

  k_pre<<<NBLK_CAST + NBLK_DEG + NBLK_PREP, 256, 0, stream>>>(
      x, xh, dstE, count, W1, W2, Wc, W1t, W2t, Wct);
  k_scan1<<<NBLK_SCAN, 256, 0, stream>>>(count, rowstart, bsum, dinv);
  k_scan2<<<1, 256, 0, stream>>>(bsum, boff);
  k_scan3<<<NBLK_SCAN, 256, 0, stream>>>(rowstart, boff);
  k_scatter<<<(NEDGES + 255) / 256, 256, 0, stream>>>(srcE, dstE, rowstart, cursor, csr);

  // layer 1
  k_agg1<<<(NNODES + 3) / 4, 256, 0, stream>>>(xh, rowstart, csr, dinv, (uint2*)aggx);
  {
    dim3 grid((NNODES + 127) / 128, HID / 128);
    k_mgemm<1, 1><<<grid, 256, 0, stream>>>(aggx, W1t, b1, (void*)h1, NNODES, HID, F_IN);
  }
  // layer 2 (aggregation split into two 128-dim halves — diagnostic + bounded)
  k_agg2h<<<(NNODES + 3) / 4, 256, 0, stream>>>(h1, rowstart, csr, dinv, aggh, 0);
  k_agg2h<<<(NNODES + 3) / 4, 256, 0, stream>>>(h1, rowstart, csr, dinv, aggh, 128);
  {
    dim3 grid((NNODES + 127) / 128, HID / 128);
    k_mgemm<1, 1><<<grid, 256, 0, stream>>>(aggh, W2t, b2, (void*)h2, NNODES, HID, HID);
  }
  // classifier
  k_cls<<<(NNODES + 255) / 256, 256, 0, stream>>>(h2, Wct, bc, out, NNODES);
}

// Round 8
// 343.348 us; speedup vs baseline: 1.0532x; 1.0532x over previous
//
#include <hip/hip_runtime.h>

#define NNODES 50000
#define NEDGES 800000
#define F_IN   128
#define HID    256
#define NOUT   40
#define NBLK_SCAN ((NNODES + 255) / 256)  // 196
#define NBLK_CAST 6250                     // 50000*128/4/256
#define NBLK_DEG  2048                     // partitioned: 256 chunks x 8 groups
#define NBLK_PREP 432                      // 128 (W1) + 256 (W2) + 48 (Wc)
#define EDGE_CHUNK 3125                    // 800000 / 256
#define NODES_PER_G 6250                   // 50000 / 8

typedef __attribute__((ext_vector_type(8))) _Float16 f16x8;
typedef __attribute__((ext_vector_type(4))) float f32x4;
typedef __attribute__((ext_vector_type(4))) unsigned short u16x4;
typedef __attribute__((ext_vector_type(8))) unsigned short u16x8;

__device__ __forceinline__ unsigned short f2h(float f) {
  return __builtin_bit_cast(unsigned short, (_Float16)f);
}
__device__ __forceinline__ float h2f(unsigned short u) {
  return (float)__builtin_bit_cast(_Float16, u);
}

// ------- fused: x->fp16 cast | XCD-local degree | weight transpose ---------
// Degree: blocks are assigned node-range group g = blockIdx&7 (HW round-robin
// XCD heuristic). Each block scans one edge chunk and counts only dst in its
// range -> count atomics stay in one XCD's L2. Wrong mapping = slower, never
// incorrect.

__global__ __launch_bounds__(256) void k_pre(const float* __restrict__ X,
                                             unsigned short* __restrict__ Xh,
                                             const int* __restrict__ dst,
                                             int* __restrict__ count,
                                             const float* __restrict__ W1,
                                             const float* __restrict__ W2,
                                             const float* __restrict__ Wc,
                                             unsigned short* __restrict__ T1,
                                             unsigned short* __restrict__ T2,
                                             unsigned short* __restrict__ Tc) {
  int b = blockIdx.x, t = threadIdx.x;
  if (b < NBLK_CAST) {
    int i = b * 256 + t;
    float4 v = *reinterpret_cast<const float4*>(X + (size_t)i * 4);
    ushort4 o;
    o.x = f2h(v.x); o.y = f2h(v.y); o.z = f2h(v.z); o.w = f2h(v.w);
    *reinterpret_cast<ushort4*>(Xh + (size_t)i * 4) = o;
  } else if (b < NBLK_CAST + NBLK_DEG) {
    int db = b - NBLK_CAST;
    int g = b & 7;                 // hardware XCD (round-robin heuristic)
    int chunk = db >> 3;           // 0..255
    int lo = g * NODES_PER_G, hi = lo + NODES_PER_G;
    int base = chunk * EDGE_CHUNK;
    for (int i = base + t; i < base + EDGE_CHUNK; i += 256) {
      int d = dst[i];
      if (d >= lo && d < hi) atomicAdd(&count[d], 1);
    }
  } else {
    int pb = b - NBLK_CAST - NBLK_DEG;  // 0..431
    if (pb < 128) {                     // W1 [128][256] -> T1 [256][128]
      int idx = pb * 256 + t;
      int n = idx >> 7, k = idx & 127;
      T1[idx] = f2h(W1[(size_t)k * HID + n]);
    } else if (pb < 384) {              // W2 [256][256] -> T2 [256][256]
      int idx = (pb - 128) * 256 + t;
      int n = idx >> 8, k = idx & 255;
      T2[idx] = f2h(W2[(size_t)k * HID + n]);
    } else {                            // Wc [256][40] -> Tc [48][256] zero-pad
      int idx = (pb - 384) * 256 + t;
      int n = idx >> 8, k = idx & 255;
      float v = (n < NOUT) ? Wc[(size_t)k * NOUT + n] : 0.f;
      Tc[idx] = f2h(v);
    }
  }
}

// ---------------- CSR scan (2 kernels; block offsets folded into consumers) -

__global__ __launch_bounds__(256) void k_scan1(const int* __restrict__ count,
                                               int* __restrict__ rowstart,
                                               int* __restrict__ bsum,
                                               float* __restrict__ dinv) {
  __shared__ int tmp[256];
  int t = threadIdx.x;
  int i = blockIdx.x * 256 + t;
  int v = (i < NNODES) ? count[i] : 0;
  if (i < NNODES) dinv[i] = rsqrtf((float)(v + 1));  // +1 self-loop
  tmp[t] = v;
  __syncthreads();
  for (int off = 1; off < 256; off <<= 1) {
    int x = (t >= off) ? tmp[t - off] : 0;
    __syncthreads();
    tmp[t] += x;
    __syncthreads();
  }
  if (i < NNODES) rowstart[i] = tmp[t] - v;  // exclusive within block
  if (t == 255) bsum[blockIdx.x] = tmp[255];
}

__global__ __launch_bounds__(256) void k_scan2(const int* __restrict__ bsum,
                                               int* __restrict__ boff) {
  __shared__ int tmp[256];
  int t = threadIdx.x;
  int v = (t < NBLK_SCAN) ? bsum[t] : 0;
  tmp[t] = v;
  __syncthreads();
  for (int off = 1; off < 256; off <<= 1) {
    int x = (t >= off) ? tmp[t - off] : 0;
    __syncthreads();
    tmp[t] += x;
    __syncthreads();
  }
  if (t < NBLK_SCAN) boff[t] = tmp[t] - v;  // exclusive
}

// ---------------- XCD-local scatter ----------------
// Same partition as degree: group g = blockIdx&7 owns nodes [g*6250,(g+1)*6250);
// csr lines + cursor atomics for those nodes live in one XCD's L2.

__global__ __launch_bounds__(256) void k_scatter(const int* __restrict__ src,
                                                 const int* __restrict__ dst,
                                                 const int* __restrict__ rowstart,
                                                 const int* __restrict__ boff,
                                                 int* __restrict__ cursor,
                                                 int* __restrict__ csr) {
  int g = blockIdx.x & 7;
  int chunk = blockIdx.x >> 3;
  int lo = g * NODES_PER_G, hi = lo + NODES_PER_G;
  int base = chunk * EDGE_CHUNK;
  for (int i = base + threadIdx.x; i < base + EDGE_CHUNK; i += 256) {
    int d = dst[i];
    if (d >= lo && d < hi) {
      int p = rowstart[d] + boff[d >> 8] + atomicAdd(&cursor[d], 1);
      csr[p] = src[i];
    }
  }
}

// ---------------- agg layer 1: half-wave fp16 gather (F=128) ----------------

__global__ __launch_bounds__(256) void k_agg1(const unsigned short* __restrict__ X,
                                              const int* __restrict__ rowstart,
                                              const int* __restrict__ boff,
                                              const int* __restrict__ csr,
                                              const float* __restrict__ dinv,
                                              uint2* __restrict__ Y) {
  int wave = threadIdx.x >> 6, lane = threadIdx.x & 63;
  int node = blockIdx.x * 4 + wave;
  if (node >= NNODES) return;
  int half = lane >> 5, l32 = lane & 31;
  float di = dinv[node];
  float a[4] = {0.f, 0.f, 0.f, 0.f};
  int e = rowstart[node] + boff[node >> 8];
  int end = (node + 1 < NNODES) ? rowstart[node + 1] + boff[(node + 1) >> 8] : NEDGES;
  for (; e + 8 <= end; e += 8) {
    int s0 = csr[e + 0 + half], s1 = csr[e + 2 + half];
    int s2 = csr[e + 4 + half], s3 = csr[e + 6 + half];
    float w0 = dinv[s0] * di, w1 = dinv[s1] * di;
    float w2 = dinv[s2] * di, w3 = dinv[s3] * di;
    u16x4 r0 = *reinterpret_cast<const u16x4*>(X + (size_t)s0 * F_IN + l32 * 4);
    u16x4 r1 = *reinterpret_cast<const u16x4*>(X + (size_t)s1 * F_IN + l32 * 4);
    u16x4 r2 = *reinterpret_cast<const u16x4*>(X + (size_t)s2 * F_IN + l32 * 4);
    u16x4 r3 = *reinterpret_cast<const u16x4*>(X + (size_t)s3 * F_IN + l32 * 4);
#pragma unroll
    for (int k = 0; k < 4; k++) {
      a[k] = fmaf(h2f(r0[k]), w0, a[k]);
      a[k] = fmaf(h2f(r1[k]), w1, a[k]);
      a[k] = fmaf(h2f(r2[k]), w2, a[k]);
      a[k] = fmaf(h2f(r3[k]), w3, a[k]);
    }
  }
  for (; e + 2 <= end; e += 2) {
    int s = csr[e + half];
    float w = dinv[s] * di;
    u16x4 r = *reinterpret_cast<const u16x4*>(X + (size_t)s * F_IN + l32 * 4);
#pragma unroll
    for (int k = 0; k < 4; k++) a[k] = fmaf(h2f(r[k]), w, a[k]);
  }
  if (e < end) {  // odd remainder: both halves read it, half 1 weight 0
    int s = csr[e];
    float w = half ? 0.f : dinv[s] * di;
    u16x4 r = *reinterpret_cast<const u16x4*>(X + (size_t)s * F_IN + l32 * 4);
#pragma unroll
    for (int k = 0; k < 4; k++) a[k] = fmaf(h2f(r[k]), w, a[k]);
  }
#pragma unroll
  for (int k = 0; k < 4; k++) a[k] += __shfl_xor(a[k], 32);
  if (half == 0) {
    u16x4 self = *reinterpret_cast<const u16x4*>(X + (size_t)node * F_IN + l32 * 4);
    float dd = di * di;
#pragma unroll
    for (int k = 0; k < 4; k++) a[k] = fmaf(h2f(self[k]), dd, a[k]);
    uint2 o;
    o.x = (unsigned)f2h(a[0]) | ((unsigned)f2h(a[1]) << 16);
    o.y = (unsigned)f2h(a[2]) | ((unsigned)f2h(a[3]) << 16);
    Y[(size_t)node * 32 + l32] = o;
  }
}

// ---------------- agg layer 2: half-wave fp16 gather (F=256) ----------------

__global__ __launch_bounds__(256) void k_agg2(const unsigned short* __restrict__ H,
                                              const int* __restrict__ rowstart,
                                              const int* __restrict__ boff,
                                              const int* __restrict__ csr,
                                              const float* __restrict__ dinv,
                                              uint4* __restrict__ Y) {
  int wave = threadIdx.x >> 6, lane = threadIdx.x & 63;
  int node = blockIdx.x * 4 + wave;
  if (node >= NNODES) return;
  int half = lane >> 5, l32 = lane & 31;
  float di = dinv[node];
  float a[8] = {0.f, 0.f, 0.f, 0.f, 0.f, 0.f, 0.f, 0.f};
  int e = rowstart[node] + boff[node >> 8];
  int end = (node + 1 < NNODES) ? rowstart[node + 1] + boff[(node + 1) >> 8] : NEDGES;
  for (; e + 8 <= end; e += 8) {
    int s0 = csr[e + 0 + half], s1 = csr[e + 2 + half];
    int s2 = csr[e + 4 + half], s3 = csr[e + 6 + half];
    float w0 = dinv[s0] * di, w1 = dinv[s1] * di;
    float w2 = dinv[s2] * di, w3 = dinv[s3] * di;
    u16x8 r0 = *reinterpret_cast<const u16x8*>(H + (size_t)s0 * HID + l32 * 8);
    u16x8 r1 = *reinterpret_cast<const u16x8*>(H + (size_t)s1 * HID + l32 * 8);
    u16x8 r2 = *reinterpret_cast<const u16x8*>(H + (size_t)s2 * HID + l32 * 8);
    u16x8 r3 = *reinterpret_cast<const u16x8*>(H + (size_t)s3 * HID + l32 * 8);
#pragma unroll
    for (int k = 0; k < 8; k++) {
      a[k] = fmaf(h2f(r0[k]), w0, a[k]);
      a[k] = fmaf(h2f(r1[k]), w1, a[k]);
      a[k] = fmaf(h2f(r2[k]), w2, a[k]);
      a[k] = fmaf(h2f(r3[k]), w3, a[k]);
    }
  }
  for (; e + 2 <= end; e += 2) {
    int s = csr[e + half];
    float w = dinv[s] * di;
    u16x8 r = *reinterpret_cast<const u16x8*>(H + (size_t)s * HID + l32 * 8);
#pragma unroll
    for (int k = 0; k < 8; k++) a[k] = fmaf(h2f(r[k]), w, a[k]);
  }
  if (e < end) {
    int s = csr[e];
    float w = half ? 0.f : dinv[s] * di;
    u16x8 r = *reinterpret_cast<const u16x8*>(H + (size_t)s * HID + l32 * 8);
#pragma unroll
    for (int k = 0; k < 8; k++) a[k] = fmaf(h2f(r[k]), w, a[k]);
  }
#pragma unroll
  for (int k = 0; k < 8; k++) a[k] += __shfl_xor(a[k], 32);
  if (half == 0) {
    u16x8 self = *reinterpret_cast<const u16x8*>(H + (size_t)node * HID + l32 * 8);
    float dd = di * di;
#pragma unroll
    for (int k = 0; k < 8; k++) a[k] = fmaf(h2f(self[k]), dd, a[k]);
    uint4 o;
    o.x = (unsigned)f2h(a[0]) | ((unsigned)f2h(a[1]) << 16);
    o.y = (unsigned)f2h(a[2]) | ((unsigned)f2h(a[3]) << 16);
    o.z = (unsigned)f2h(a[4]) | ((unsigned)f2h(a[5]) << 16);
    o.w = (unsigned)f2h(a[6]) | ((unsigned)f2h(a[7]) << 16);
    Y[(size_t)node * 32 + l32] = o;
  }
}

// ---------------- fp16 MFMA GEMM, double-buffered, 1 barrier/K-step --------
// C = A[MxK] @ B[KxN] + bias. A fp16 [M][K]; B fp16 transposed [Npad][K].
// BM=BN=128, BK=32, 4 waves (2x2). OMODE: 0 = f32 out, 1 = fp16 out.

template <int RELU, int OMODE>
__global__ __launch_bounds__(256) void k_mgemm(const unsigned short* __restrict__ Ag,
                                               const unsigned short* __restrict__ Btg,
                                               const float* __restrict__ bias,
                                               void* __restrict__ Cout,
                                               int M, int Nc, int K) {
  __shared__ unsigned short Ah[2][128 * 40];
  __shared__ unsigned short Bh[2][128 * 40];
  int tid = threadIdx.x;
  int lane = tid & 63, w = tid >> 6;
  int wr = w >> 1, wc = w & 1;
  int bm = blockIdx.x * 128, bn = blockIdx.y * 128;
  int l15 = lane & 15, kg = lane >> 4;
  int row0 = tid >> 2, kq0 = (tid & 3) * 8;
  int gm0 = bm + row0, gm1 = bm + row0 + 64;

  f32x4 zero = {0.f, 0.f, 0.f, 0.f};
  f32x4 acc[4][4];
#pragma unroll
  for (int i = 0; i < 4; i++)
#pragma unroll
    for (int j = 0; j < 4; j++) acc[i][j] = zero;

  uint4 ra0, ra1, rb0, rb1;
  const uint4 z4 = {0, 0, 0, 0};
#define LOADT(KT)                                                                    \
  {                                                                                  \
    ra0 = z4; ra1 = z4;                                                              \
    if (gm0 < M) ra0 = *reinterpret_cast<const uint4*>(Ag + (size_t)gm0 * K + (KT) + kq0); \
    if (gm1 < M) ra1 = *reinterpret_cast<const uint4*>(Ag + (size_t)gm1 * K + (KT) + kq0); \
    rb0 = *reinterpret_cast<const uint4*>(Btg + (size_t)(bn + row0) * K + (KT) + kq0);     \
    rb1 = *reinterpret_cast<const uint4*>(Btg + (size_t)(bn + row0 + 64) * K + (KT) + kq0);\
  }
#define STORET(B)                                                       \
  {                                                                     \
    *reinterpret_cast<uint4*>(&Ah[B][row0 * 40 + kq0]) = ra0;           \
    *reinterpret_cast<uint4*>(&Ah[B][(row0 + 64) * 40 + kq0]) = ra1;    \
    *reinterpret_cast<uint4*>(&Bh[B][row0 * 40 + kq0]) = rb0;           \
    *reinterpret_cast<uint4*>(&Bh[B][(row0 + 64) * 40 + kq0]) = rb1;    \
  }

  LOADT(0);
  STORET(0);
  __syncthreads();
  int nt = K >> 5, cur = 0;
  for (int t = 0; t < nt; t++) {
    bool pf = (t + 1 < nt);
    if (pf) LOADT((t + 1) << 5);
    f16x8 fa[4], fb[4];
#pragma unroll
    for (int f = 0; f < 4; f++) {
      fa[f] = *reinterpret_cast<const f16x8*>(&Ah[cur][(wr * 64 + f * 16 + l15) * 40 + kg * 8]);
      fb[f] = *reinterpret_cast<const f16x8*>(&Bh[cur][(wc * 64 + f * 16 + l15) * 40 + kg * 8]);
    }
#pragma unroll
    for (int i = 0; i < 4; i++)
#pragma unroll
      for (int j = 0; j < 4; j++)
        acc[i][j] = __builtin_amdgcn_mfma_f32_16x16x32_f16(fa[i], fb[j], acc[i][j], 0, 0, 0);
    if (pf) STORET(cur ^ 1);
    __syncthreads();
    cur ^= 1;
  }
#undef LOADT
#undef STORET

  int r0 = kg * 4;
#pragma unroll
  for (int i = 0; i < 4; i++) {
    int gmBase = bm + wr * 64 + i * 16 + r0;
#pragma unroll
    for (int r = 0; r < 4; r++) {
      int gm = gmBase + r;
      if (gm >= M) continue;
#pragma unroll
      for (int j = 0; j < 4; j++) {
        int gn = bn + wc * 64 + j * 16 + l15;
        if (gn >= Nc) continue;
        float v = acc[i][j][r] + bias[gn];
        if (RELU) v = fmaxf(v, 0.f);
        size_t o = (size_t)gm * Nc + gn;
        if (OMODE == 0) ((float*)Cout)[o] = v;
        else            ((unsigned short*)Cout)[o] = f2h(v);
      }
    }
  }
}

// ---------------- classifier: BM=256, BN=48 (NOUT=40), fp32 out -------------

__global__ __launch_bounds__(256) void k_cls(const unsigned short* __restrict__ Ag,
                                             const unsigned short* __restrict__ Btg,
                                             const float* __restrict__ bias,
                                             float* __restrict__ C, int M) {
  __shared__ unsigned short As[256 * 40];
  __shared__ unsigned short Bs[48 * 40];
  int tid = threadIdx.x;
  int lane = tid & 63, w = tid >> 6;
  int l15 = lane & 15, kg = lane >> 4;
  int bm = blockIdx.x * 256;

  f32x4 zero = {0.f, 0.f, 0.f, 0.f};
  f32x4 acc[4][3];
#pragma unroll
  for (int i = 0; i < 4; i++)
#pragma unroll
    for (int j = 0; j < 3; j++) acc[i][j] = zero;

  for (int kt = 0; kt < HID; kt += 32) {
#pragma unroll
    for (int it = 0; it < 4; it++) {
      int c = tid + it * 256;
      int row = c >> 2, kq = (c & 3) * 8;
      int gm = bm + row;
      uint4 v = {0, 0, 0, 0};
      if (gm < M) v = *reinterpret_cast<const uint4*>(Ag + (size_t)gm * HID + kt + kq);
      *reinterpret_cast<uint4*>(&As[row * 40 + kq]) = v;
    }
    if (tid < 192) {
      int row = tid >> 2, kq = (tid & 3) * 8;
      *reinterpret_cast<uint4*>(&Bs[row * 40 + kq]) =
          *reinterpret_cast<const uint4*>(Btg + (size_t)row * HID + kt + kq);
    }
    __syncthreads();
    f16x8 fa[4], fb[3];
#pragma unroll
    for (int f = 0; f < 4; f++)
      fa[f] = *reinterpret_cast<const f16x8*>(&As[(w * 64 + f * 16 + l15) * 40 + kg * 8]);
#pragma unroll
    for (int j = 0; j < 3; j++)
      fb[j] = *reinterpret_cast<const f16x8*>(&Bs[(j * 16 + l15) * 40 + kg * 8]);
#pragma unroll
    for (int i = 0; i < 4; i++)
#pragma unroll
      for (int j = 0; j < 3; j++)
        acc[i][j] = __builtin_amdgcn_mfma_f32_16x16x32_f16(fa[i], fb[j], acc[i][j], 0, 0, 0);
    __syncthreads();
  }

  int r0 = kg * 4;
#pragma unroll
  for (int i = 0; i < 4; i++) {
    int gmBase = bm + w * 64 + i * 16 + r0;
#pragma unroll
    for (int r = 0; r < 4; r++) {
      int gm = gmBase + r;
      if (gm >= M) continue;
#pragma unroll
      for (int j = 0; j < 3; j++) {
        int gn = j * 16 + l15;
        if (gn >= NOUT) continue;
        C[(size_t)gm * NOUT + gn] = acc[i][j][r] + bias[gn];
      }
    }
  }
}

// ---------------- launch ----------------

extern "C" void kernel_launch(void* const* d_in, const int* in_sizes, int n_in,
                              void* d_out, int out_size, void* d_ws, size_t ws_size,
                              hipStream_t stream) {
  (void)in_sizes; (void)n_in; (void)out_size; (void)ws_size;
  const float* x  = (const float*)d_in[0];
  const float* W1 = (const float*)d_in[1];
  const float* b1 = (const float*)d_in[2];
  const float* W2 = (const float*)d_in[3];
  const float* b2 = (const float*)d_in[4];
  const float* Wc = (const float*)d_in[5];
  const float* bc = (const float*)d_in[6];
  const int* edge = (const int*)d_in[7];
  const int* srcE = edge;
  const int* dstE = edge + NEDGES;
  float* out = (float*)d_out;

  char* ws = (char*)d_ws;
  int*   count    = (int*)(ws + 0);          // 200000 B
  int*   cursor   = (int*)(ws + 200064);
  int*   rowstart = (int*)(ws + 400128);     // 200004 B (per-block partial)
  float* dinv     = (float*)(ws + 600320);
  int*   csr      = (int*)(ws + 800384);     // 3.2 MB
  int*   bsum     = (int*)(ws + 4000512);
  int*   boff     = (int*)(ws + 4001536);
  unsigned short* W1t = (unsigned short*)(ws + 4002560);   // 256x128 fp16
  unsigned short* W2t = (unsigned short*)(ws + 4068096);   // 256x256 fp16
  unsigned short* Wct = (unsigned short*)(ws + 4199168);   // 48x256 fp16
  unsigned short* xh  = (unsigned short*)(ws + 4264704);   // 50000x128 fp16
  unsigned short* aggx = (unsigned short*)(ws + 17064704); // 50000x128 fp16
  unsigned short* h1   = (unsigned short*)(ws + 29864704); // 50000x256 fp16
  unsigned short* aggh = (unsigned short*)(ws + 55464704); // 50000x256 fp16
  unsigned short* h2   = (unsigned short*)(ws + 81064704); // 50000x256 fp16

  hipMemsetAsync(ws, 0, 400128, stream);  // count + cursor

  k_pre<<<NBLK_CAST + NBLK_DEG + NBLK_PREP, 256, 0, stream>>>(
      x, xh, dstE, count, W1, W2, Wc, W1t, W2t, Wct);
  k_scan1<<<NBLK_SCAN, 256, 0, stream>>>(count, rowstart, bsum, dinv);
  k_scan2<<<1, 256, 0, stream>>>(bsum, boff);
  k_scatter<<<NBLK_DEG, 256, 0, stream>>>(srcE, dstE, rowstart, boff, cursor, csr);

  // layer 1
  k_agg1<<<(NNODES + 3) / 4, 256, 0, stream>>>(xh, rowstart, boff, csr, dinv, (uint2*)aggx);
  {
    dim3 grid((NNODES + 127) / 128, HID / 128);
    k_mgemm<1, 1><<<grid, 256, 0, stream>>>(aggx, W1t, b1, (void*)h1, NNODES, HID, F_IN);
  }
  // layer 2
  k_agg2<<<(NNODES + 3) / 4, 256, 0, stream>>>(h1, rowstart, boff, csr, dinv, (uint4*)aggh);
  {
    dim3 grid((NNODES + 127) / 128, HID / 128);
    k_mgemm<1, 1><<<grid, 256, 0, stream>>>(aggh, W2t, b2, (void*)h2, NNODES, HID, HID);
  }
  // classifier
  k_cls<<<(NNODES + 255) / 256, 256, 0, stream>>>(h2, Wct, bc, out, NNODES);
}